// Round 1
// baseline (602.748 us; speedup 1.0000x reference)
//
#include <hip/hip_runtime.h>
#include <hip/hip_bf16.h>
#include <stdint.h>

typedef __bf16 bf16x8 __attribute__((ext_vector_type(8)));
typedef float f32x4 __attribute__((ext_vector_type(4)));
typedef unsigned short ushort8v __attribute__((ext_vector_type(8)));
typedef unsigned short ushort4v __attribute__((ext_vector_type(4)));

#define MFMA16(a, b, c) __builtin_amdgcn_mfma_f32_16x16x32_bf16(a, b, c, 0, 0, 0)

__device__ __forceinline__ unsigned short f2bf_u(float f) {
    union { float f; uint32_t u; } cv; cv.f = f;
    uint32_t u = cv.u;
    uint32_t r = (u + 0x7FFFu + ((u >> 16) & 1u)) >> 16;
    return (unsigned short)r;
}

// ---------------------------------------------------------------------------
// Transpose + cast: Wt[n][k] = bf16(W[k][n]),  W is 1024x1024 fp32 row-major
// ---------------------------------------------------------------------------
__global__ __launch_bounds__(256) void wt_cast(const float* __restrict__ W,
                                               unsigned short* __restrict__ Wt) {
    __shared__ float t[32][33];
    const int tx = threadIdx.x & 31, ty = threadIdx.x >> 5;  // 32 x 8
    const int n0 = blockIdx.x * 32, k0 = blockIdx.y * 32;
#pragma unroll
    for (int i = 0; i < 4; i++) {
        int r = i * 8 + ty;
        t[r][tx] = W[(size_t)(k0 + r) * 1024 + n0 + tx];
    }
    __syncthreads();
#pragma unroll
    for (int i = 0; i < 4; i++) {
        int r = i * 8 + ty;
        Wt[(size_t)(n0 + r) * 1024 + k0 + tx] = f2bf_u(t[tx][r]);
    }
}

// ---------------------------------------------------------------------------
// QKV GEMM: out = relu(A[8192x1024] @ W + bias), A fp32, Wt bf16 [N][K].
// VT_LAYOUT==0: out[((b*16+h)*2048+s)*64+d]   (Q,K: [B,H,S,dh])
// VT_LAYOUT==1: out[((b*16+h)*64+d)*2048+s]   (V transposed: [B,H,dh,S])
// 128x128 tile, 4 waves (2x2 of 64x64), BK=32, mfma 16x16x32 bf16.
// ---------------------------------------------------------------------------
template <int VT_LAYOUT>
__global__ __launch_bounds__(256) void qkv_gemm(const float* __restrict__ A,
                                                const unsigned short* __restrict__ Wt,
                                                const float* __restrict__ bias,
                                                unsigned short* __restrict__ out) {
    __shared__ unsigned short aS[128 * 32];
    __shared__ unsigned short wS[128 * 32];
    const int tid = threadIdx.x;
    const int lane = tid & 63, wave = tid >> 6;
    const int rrow = lane & 15, rgrp = lane >> 4;
    const int m0 = blockIdx.y * 128, n0 = blockIdx.x * 128;
    const int wm = wave >> 1, wn = wave & 1;

    f32x4 acc[4][4];
#pragma unroll
    for (int i = 0; i < 4; i++)
#pragma unroll
        for (int j = 0; j < 4; j++) acc[i][j] = (f32x4)0.0f;

    for (int k0 = 0; k0 < 1024; k0 += 32) {
        __syncthreads();
#pragma unroll
        for (int it = 0; it < 2; it++) {
            const int c = tid + it * 256;          // 512 chunks: 128 rows x 4 k-chunks
            const int row = c >> 2, kc = c & 3;
            const int off = (row * 64 + kc * 16) ^ ((row & 7) << 4);
            // A: fp32 -> bf16
            const float4* ap =
                reinterpret_cast<const float4*>(A + (size_t)(m0 + row) * 1024 + k0 + kc * 8);
            float4 f0 = ap[0], f1 = ap[1];
            ushort8v av;
            av[0] = f2bf_u(f0.x); av[1] = f2bf_u(f0.y); av[2] = f2bf_u(f0.z); av[3] = f2bf_u(f0.w);
            av[4] = f2bf_u(f1.x); av[5] = f2bf_u(f1.y); av[6] = f2bf_u(f1.z); av[7] = f2bf_u(f1.w);
            *reinterpret_cast<ushort8v*>(reinterpret_cast<char*>(aS) + off) = av;
            // W: already bf16
            ushort8v wv = *reinterpret_cast<const ushort8v*>(
                Wt + (size_t)(n0 + row) * 1024 + k0 + kc * 8);
            *reinterpret_cast<ushort8v*>(reinterpret_cast<char*>(wS) + off) = wv;
        }
        __syncthreads();

        bf16x8 af[4], bfr[4];
#pragma unroll
        for (int mi = 0; mi < 4; mi++) {
            const int r = wm * 64 + mi * 16 + rrow;
            const int off = (r * 64 + rgrp * 16) ^ ((r & 7) << 4);
            af[mi] = *reinterpret_cast<const bf16x8*>(reinterpret_cast<const char*>(aS) + off);
        }
#pragma unroll
        for (int ni = 0; ni < 4; ni++) {
            const int r = wn * 64 + ni * 16 + rrow;
            const int off = (r * 64 + rgrp * 16) ^ ((r & 7) << 4);
            bfr[ni] = *reinterpret_cast<const bf16x8*>(reinterpret_cast<const char*>(wS) + off);
        }
#pragma unroll
        for (int mi = 0; mi < 4; mi++)
#pragma unroll
            for (int ni = 0; ni < 4; ni++)
                acc[mi][ni] = MFMA16(af[mi], bfr[ni], acc[mi][ni]);
    }

    // Epilogue: bias + relu + bf16, scatter into head-split layout.
#pragma unroll
    for (int mi = 0; mi < 4; mi++) {
#pragma unroll
        for (int ni = 0; ni < 4; ni++) {
            const int n = n0 + wn * 64 + ni * 16 + rrow;
            const float bv = bias[n];
            const int h = n >> 6, d = n & 63;
            const int mbase = m0 + wm * 64 + mi * 16 + rgrp * 4;
            const int b = mbase >> 11, s = mbase & 2047;
            if (VT_LAYOUT) {
                ushort4v pv;
#pragma unroll
                for (int jr = 0; jr < 4; jr++)
                    pv[jr] = f2bf_u(fmaxf(acc[mi][ni][jr] + bv, 0.0f));
                *reinterpret_cast<ushort4v*>(out + ((size_t)((b * 16 + h) * 64 + d)) * 2048 + s) = pv;
            } else {
#pragma unroll
                for (int jr = 0; jr < 4; jr++)
                    out[((size_t)((b * 16 + h) * 2048 + (s + jr))) * 64 + d] =
                        f2bf_u(fmaxf(acc[mi][ni][jr] + bv, 0.0f));
            }
        }
    }
}

// ---------------------------------------------------------------------------
// Flash attention. Q,K: [B,H,S,64] bf16.  Vt: [B,H,64,S] bf16.
// Each block: one (b,h), 64 q-rows; each of 4 waves owns 16 q-rows.
// K/V fragments read directly from global (L2/L3-resident, 512KB per head).
// ---------------------------------------------------------------------------
__global__ __launch_bounds__(256) void flash_attn(const unsigned short* __restrict__ Qg,
                                                  const unsigned short* __restrict__ Kg,
                                                  const unsigned short* __restrict__ Vt,
                                                  const int* __restrict__ mask,
                                                  float* __restrict__ O) {
    __shared__ unsigned short ptile[4][16 * 72];  // per-wave P tile, stride 72 (144B, 16B-mult)
    const int tid = threadIdx.x, lane = tid & 63, wave = tid >> 6;
    const int rrow = lane & 15, rgrp = lane >> 4;
    const int qt = blockIdx.x, bh = blockIdx.y;
    const int b = bh >> 4, h = bh & 15;
    const size_t base = (size_t)bh * (2048 * 64);
    const unsigned short* Qb = Qg + base;
    const unsigned short* Kb = Kg + base;
    const unsigned short* Vb = Vt + base;  // [64][2048]
    const int q0 = qt * 64 + wave * 16;

    bf16x8 aq[2];
#pragma unroll
    for (int kb = 0; kb < 2; kb++)
        aq[kb] = *reinterpret_cast<const bf16x8*>(Qb + (size_t)(q0 + rrow) * 64 + rgrp * 8 + kb * 32);

    int mk[4];
#pragma unroll
    for (int jr = 0; jr < 4; jr++) mk[jr] = mask[b * 2048 + q0 + rgrp * 4 + jr];

    float mrow[4] = {-1e30f, -1e30f, -1e30f, -1e30f};
    float lsum[4] = {0.f, 0.f, 0.f, 0.f};
    f32x4 oacc[4];
#pragma unroll
    for (int i = 0; i < 4; i++) oacc[i] = (f32x4)0.0f;

    unsigned short* pw = ptile[wave];

    for (int kt = 0; kt < 32; kt++) {
        // ---- S = Q K^T (16 x 64) ----
        f32x4 sacc[4];
#pragma unroll
        for (int i = 0; i < 4; i++) sacc[i] = (f32x4)0.0f;
#pragma unroll
        for (int ni = 0; ni < 4; ni++) {
#pragma unroll
            for (int kb = 0; kb < 2; kb++) {
                bf16x8 bk = *reinterpret_cast<const bf16x8*>(
                    Kb + (size_t)(kt * 64 + ni * 16 + rrow) * 64 + rgrp * 8 + kb * 32);
                sacc[ni] = MFMA16(aq[kb], bk, sacc[ni]);
            }
        }
        // ---- scale + mask + row max ----
        float pm[4];
#pragma unroll
        for (int jr = 0; jr < 4; jr++) {
            float v0 = sacc[0][jr] * 0.125f, v1 = sacc[1][jr] * 0.125f;
            float v2 = sacc[2][jr] * 0.125f, v3 = sacc[3][jr] * 0.125f;
            if (!mk[jr]) { v0 = v1 = v2 = v3 = 1e-9f; }
            sacc[0][jr] = v0; sacc[1][jr] = v1; sacc[2][jr] = v2; sacc[3][jr] = v3;
            float t = fmaxf(fmaxf(v0, v1), fmaxf(v2, v3));
            t = fmaxf(t, __shfl_xor(t, 1, 64));
            t = fmaxf(t, __shfl_xor(t, 2, 64));
            t = fmaxf(t, __shfl_xor(t, 4, 64));
            t = fmaxf(t, __shfl_xor(t, 8, 64));
            pm[jr] = t;
        }
        // ---- online softmax update ----
        float alpha[4];
#pragma unroll
        for (int jr = 0; jr < 4; jr++) {
            const float mn = fmaxf(mrow[jr], pm[jr]);
            alpha[jr] = __expf(mrow[jr] - mn);
            mrow[jr] = mn;
            float s = 0.f;
#pragma unroll
            for (int ni = 0; ni < 4; ni++) {
                float p = __expf(sacc[ni][jr] - mn);
                sacc[ni][jr] = p;
                s += p;
            }
            s += __shfl_xor(s, 1, 64);
            s += __shfl_xor(s, 2, 64);
            s += __shfl_xor(s, 4, 64);
            s += __shfl_xor(s, 8, 64);
            lsum[jr] = lsum[jr] * alpha[jr] + s;
        }
#pragma unroll
        for (int ni = 0; ni < 4; ni++)
#pragma unroll
            for (int jr = 0; jr < 4; jr++) oacc[ni][jr] *= alpha[jr];

        // ---- P -> LDS (transpose to A-fragment layout) ----
#pragma unroll
        for (int ni = 0; ni < 4; ni++)
#pragma unroll
            for (int jr = 0; jr < 4; jr++)
                pw[(rgrp * 4 + jr) * 72 + ni * 16 + rrow] = f2bf_u(sacc[ni][jr]);

        bf16x8 pa[2];
#pragma unroll
        for (int kb = 0; kb < 2; kb++)
            pa[kb] = *reinterpret_cast<const bf16x8*>(
                reinterpret_cast<const char*>(pw) + rrow * 144 + rgrp * 16 + kb * 64);

        // ---- O += P V ----
#pragma unroll
        for (int ni = 0; ni < 4; ni++) {
#pragma unroll
            for (int kb = 0; kb < 2; kb++) {
                bf16x8 bv = *reinterpret_cast<const bf16x8*>(
                    Vb + (size_t)(ni * 16 + rrow) * 2048 + kt * 64 + kb * 32 + rgrp * 8);
                oacc[ni] = MFMA16(pa[kb], bv, oacc[ni]);
            }
        }
    }

    // ---- normalize + write O (fp32, [B,S,D]) ----
    float inv[4];
#pragma unroll
    for (int jr = 0; jr < 4; jr++) inv[jr] = 1.0f / lsum[jr];
#pragma unroll
    for (int ni = 0; ni < 4; ni++)
#pragma unroll
        for (int jr = 0; jr < 4; jr++)
            O[(size_t)(b * 2048 + q0 + rgrp * 4 + jr) * 1024 + h * 64 + ni * 16 + rrow] =
                oacc[ni][jr] * inv[jr];
}

// ---------------------------------------------------------------------------
// Residual + LayerNorm: out = LN(O + queries) * gamma + beta, per row of 1024.
// ---------------------------------------------------------------------------
__global__ __launch_bounds__(256) void resid_ln(const float* __restrict__ O,
                                                const float* __restrict__ Qin,
                                                const float* __restrict__ gamma,
                                                const float* __restrict__ beta,
                                                float* __restrict__ out) {
    __shared__ float red[4];
    const int row = blockIdx.x, tid = threadIdx.x;
    const size_t base = (size_t)row * 1024 + tid * 4;
    float4 o4 = *reinterpret_cast<const float4*>(O + base);
    float4 q4 = *reinterpret_cast<const float4*>(Qin + base);
    float x0 = o4.x + q4.x, x1 = o4.y + q4.y, x2 = o4.z + q4.z, x3 = o4.w + q4.w;

    float s = x0 + x1 + x2 + x3;
#pragma unroll
    for (int off = 32; off >= 1; off >>= 1) s += __shfl_xor(s, off, 64);
    const int w = tid >> 6;
    if ((tid & 63) == 0) red[w] = s;
    __syncthreads();
    const float mean = (red[0] + red[1] + red[2] + red[3]) * (1.0f / 1024.0f);
    __syncthreads();

    const float d0 = x0 - mean, d1 = x1 - mean, d2 = x2 - mean, d3 = x3 - mean;
    float vs = d0 * d0 + d1 * d1 + d2 * d2 + d3 * d3;
#pragma unroll
    for (int off = 32; off >= 1; off >>= 1) vs += __shfl_xor(vs, off, 64);
    if ((tid & 63) == 0) red[w] = vs;
    __syncthreads();
    const float var = (red[0] + red[1] + red[2] + red[3]) * (1.0f / 1024.0f);
    const float rstd = rsqrtf(var + 1e-5f);

    float4 g = *reinterpret_cast<const float4*>(gamma + tid * 4);
    float4 be = *reinterpret_cast<const float4*>(beta + tid * 4);
    float4 r;
    r.x = d0 * rstd * g.x + be.x;
    r.y = d1 * rstd * g.y + be.y;
    r.z = d2 * rstd * g.z + be.z;
    r.w = d3 * rstd * g.w + be.w;
    *reinterpret_cast<float4*>(out + base) = r;
}

// ---------------------------------------------------------------------------
extern "C" void kernel_launch(void* const* d_in, const int* in_sizes, int n_in,
                              void* d_out, int out_size, void* d_ws, size_t ws_size,
                              hipStream_t stream) {
    const float* q_in = (const float*)d_in[0];
    const float* k_in = (const float*)d_in[1];
    const float* v_in = (const float*)d_in[2];
    const int* mask = (const int*)d_in[3];
    const float* Wq = (const float*)d_in[4];
    const float* bq = (const float*)d_in[5];
    const float* Wk = (const float*)d_in[6];
    const float* bk = (const float*)d_in[7];
    const float* Wv = (const float*)d_in[8];
    const float* bv = (const float*)d_in[9];
    const float* gamma = (const float*)d_in[10];
    const float* beta = (const float*)d_in[11];
    float* out = (float*)d_out;

    unsigned short* wtq = (unsigned short*)d_ws;         // 1M bf16
    unsigned short* wtk = wtq + 1024 * 1024;
    unsigned short* wtv = wtk + 1024 * 1024;
    unsigned short* Qb = wtv + 1024 * 1024;              // 8M bf16 each
    unsigned short* Kb = Qb + 8192 * 1024;
    unsigned short* Vtb = Kb + 8192 * 1024;
    float* Obuf = (float*)(Vtb + 8192 * 1024);           // 8M fp32

    dim3 tb(256);
    wt_cast<<<dim3(32, 32), tb, 0, stream>>>(Wq, wtq);
    wt_cast<<<dim3(32, 32), tb, 0, stream>>>(Wk, wtk);
    wt_cast<<<dim3(32, 32), tb, 0, stream>>>(Wv, wtv);
    qkv_gemm<0><<<dim3(8, 64), tb, 0, stream>>>(q_in, wtq, bq, Qb);
    qkv_gemm<0><<<dim3(8, 64), tb, 0, stream>>>(k_in, wtk, bk, Kb);
    qkv_gemm<1><<<dim3(8, 64), tb, 0, stream>>>(v_in, wtv, bv, Vtb);
    flash_attn<<<dim3(32, 64), tb, 0, stream>>>(Qb, Kb, Vtb, mask, Obuf);
    resid_ln<<<dim3(8192), tb, 0, stream>>>(Obuf, q_in, gamma, beta, out);
}

// Round 2
// 385.090 us; speedup vs baseline: 1.5652x; 1.5652x over previous
//
#include <hip/hip_runtime.h>
#include <hip/hip_bf16.h>
#include <stdint.h>

typedef __bf16 bf16x8 __attribute__((ext_vector_type(8)));
typedef float f32x4 __attribute__((ext_vector_type(4)));
typedef float f32x16 __attribute__((ext_vector_type(16)));
typedef unsigned short ushort8v __attribute__((ext_vector_type(8)));
typedef unsigned short ushort4v __attribute__((ext_vector_type(4)));

#define MFMA16(a, b, c) __builtin_amdgcn_mfma_f32_16x16x32_bf16(a, b, c, 0, 0, 0)
#define MFMA32(a, b, c) __builtin_amdgcn_mfma_f32_32x32x16_bf16(a, b, c, 0, 0, 0)

__device__ __forceinline__ unsigned short f2bf_u(float f) {
    union { float f; uint32_t u; } cv; cv.f = f;
    uint32_t u = cv.u;
    uint32_t r = (u + 0x7FFFu + ((u >> 16) & 1u)) >> 16;
    return (unsigned short)r;
}

__device__ __forceinline__ uint32_t pkbf(float a, float b) {
    // pack 2 fp32 -> 2 bf16 (a in low 16, b in high 16)
    union { __hip_bfloat162 h; uint32_t u; } cv;
    cv.h = __float22bfloat162_rn(make_float2(a, b));
    return cv.u;
}

// ---------------------------------------------------------------------------
// Transpose + cast: Wt[n][k] = bf16(W[k][n]),  W is 1024x1024 fp32 row-major
// ---------------------------------------------------------------------------
__global__ __launch_bounds__(256) void wt_cast(const float* __restrict__ W,
                                               unsigned short* __restrict__ Wt) {
    __shared__ float t[32][33];
    const int tx = threadIdx.x & 31, ty = threadIdx.x >> 5;  // 32 x 8
    const int n0 = blockIdx.x * 32, k0 = blockIdx.y * 32;
#pragma unroll
    for (int i = 0; i < 4; i++) {
        int r = i * 8 + ty;
        t[r][tx] = W[(size_t)(k0 + r) * 1024 + n0 + tx];
    }
    __syncthreads();
#pragma unroll
    for (int i = 0; i < 4; i++) {
        int r = i * 8 + ty;
        Wt[(size_t)(n0 + r) * 1024 + k0 + tx] = f2bf_u(t[tx][r]);
    }
}

// ---------------------------------------------------------------------------
// QKV GEMM: out = relu(A[8192x1024] @ W + bias), A fp32, Wt bf16 [N][K].
// VT_LAYOUT==0: out[((b*16+h)*2048+s)*64+d]   (Q,K: [B,H,S,dh])
// VT_LAYOUT==1: out[((b*16+h)*64+d)*2048+s]   (V transposed: [B,H,dh,S])
// ---------------------------------------------------------------------------
template <int VT_LAYOUT>
__global__ __launch_bounds__(256) void qkv_gemm(const float* __restrict__ A,
                                                const unsigned short* __restrict__ Wt,
                                                const float* __restrict__ bias,
                                                unsigned short* __restrict__ out) {
    __shared__ unsigned short aS[128 * 32];
    __shared__ unsigned short wS[128 * 32];
    const int tid = threadIdx.x;
    const int lane = tid & 63, wave = tid >> 6;
    const int rrow = lane & 15, rgrp = lane >> 4;
    const int m0 = blockIdx.y * 128, n0 = blockIdx.x * 128;
    const int wm = wave >> 1, wn = wave & 1;

    f32x4 acc[4][4];
#pragma unroll
    for (int i = 0; i < 4; i++)
#pragma unroll
        for (int j = 0; j < 4; j++) acc[i][j] = (f32x4)0.0f;

    for (int k0 = 0; k0 < 1024; k0 += 32) {
        __syncthreads();
#pragma unroll
        for (int it = 0; it < 2; it++) {
            const int c = tid + it * 256;          // 512 chunks: 128 rows x 4 k-chunks
            const int row = c >> 2, kc = c & 3;
            const int off = (row * 64 + kc * 16) ^ ((row & 7) << 4);
            const float4* ap =
                reinterpret_cast<const float4*>(A + (size_t)(m0 + row) * 1024 + k0 + kc * 8);
            float4 f0 = ap[0], f1 = ap[1];
            ushort8v av;
            av[0] = f2bf_u(f0.x); av[1] = f2bf_u(f0.y); av[2] = f2bf_u(f0.z); av[3] = f2bf_u(f0.w);
            av[4] = f2bf_u(f1.x); av[5] = f2bf_u(f1.y); av[6] = f2bf_u(f1.z); av[7] = f2bf_u(f1.w);
            *reinterpret_cast<ushort8v*>(reinterpret_cast<char*>(aS) + off) = av;
            ushort8v wv = *reinterpret_cast<const ushort8v*>(
                Wt + (size_t)(n0 + row) * 1024 + k0 + kc * 8);
            *reinterpret_cast<ushort8v*>(reinterpret_cast<char*>(wS) + off) = wv;
        }
        __syncthreads();

        bf16x8 af[4], bfr[4];
#pragma unroll
        for (int mi = 0; mi < 4; mi++) {
            const int r = wm * 64 + mi * 16 + rrow;
            const int off = (r * 64 + rgrp * 16) ^ ((r & 7) << 4);
            af[mi] = *reinterpret_cast<const bf16x8*>(reinterpret_cast<const char*>(aS) + off);
        }
#pragma unroll
        for (int ni = 0; ni < 4; ni++) {
            const int r = wn * 64 + ni * 16 + rrow;
            const int off = (r * 64 + rgrp * 16) ^ ((r & 7) << 4);
            bfr[ni] = *reinterpret_cast<const bf16x8*>(reinterpret_cast<const char*>(wS) + off);
        }
#pragma unroll
        for (int mi = 0; mi < 4; mi++)
#pragma unroll
            for (int ni = 0; ni < 4; ni++)
                acc[mi][ni] = MFMA16(af[mi], bfr[ni], acc[mi][ni]);
    }

#pragma unroll
    for (int mi = 0; mi < 4; mi++) {
#pragma unroll
        for (int ni = 0; ni < 4; ni++) {
            const int n = n0 + wn * 64 + ni * 16 + rrow;
            const float bv = bias[n];
            const int h = n >> 6, d = n & 63;
            const int mbase = m0 + wm * 64 + mi * 16 + rgrp * 4;
            const int b = mbase >> 11, s = mbase & 2047;
            if (VT_LAYOUT) {
                ushort4v pv;
#pragma unroll
                for (int jr = 0; jr < 4; jr++)
                    pv[jr] = f2bf_u(fmaxf(acc[mi][ni][jr] + bv, 0.0f));
                *reinterpret_cast<ushort4v*>(out + ((size_t)((b * 16 + h) * 64 + d)) * 2048 + s) = pv;
            } else {
#pragma unroll
                for (int jr = 0; jr < 4; jr++)
                    out[((size_t)((b * 16 + h) * 2048 + (s + jr))) * 64 + d] =
                        f2bf_u(fmaxf(acc[mi][ni][jr] + bv, 0.0f));
            }
        }
    }
}

// ---------------------------------------------------------------------------
// Flash attention, swapped-QK^T 32x32 structure (zero LDS).
// Q,K: [B,H,S,64] bf16.  Vt: [B,H,64,S] bf16.
// Block = 4 waves; each wave owns 32 q-rows of one (b,h). Lane owns q=lane&31.
// Per 64-key tile: S^T = mfma32(K,Q) -> in-lane softmax -> in-reg P pack
// (16 cvt_pk + 8 shfl_xor(32)) -> O += mfma32(P, V). Defer-max THR=8.
// ---------------------------------------------------------------------------
__global__ __launch_bounds__(256) void flash_attn(const unsigned short* __restrict__ Qg,
                                                  const unsigned short* __restrict__ Kg,
                                                  const unsigned short* __restrict__ Vt,
                                                  const int* __restrict__ mask,
                                                  float* __restrict__ O) {
    const int tid = threadIdx.x, lane = tid & 63, wave = tid >> 6;
    const int c = lane & 31, hi = lane >> 5;
    const int qt = blockIdx.x, bh = blockIdx.y;
    const int b = bh >> 4, h = bh & 15;
    const size_t base = (size_t)bh * (2048 * 64);
    const unsigned short* Qb = Qg + base;
    const unsigned short* Kb = Kg + base;
    const unsigned short* Vb = Vt + base;  // [64][2048]
    const int q0 = qt * 128 + wave * 32;

    // Q B-fragments: qf[ds] = Q[q0+c][ds*16 + hi*8 .. +7]
    bf16x8 qf[4];
#pragma unroll
    for (int ds = 0; ds < 4; ds++)
        qf[ds] = *reinterpret_cast<const bf16x8*>(Qb + (size_t)(q0 + c) * 64 + ds * 16 + hi * 8);

    const int mk = mask[b * 2048 + q0 + c];

    float m = 0.0f, l = 0.0f;
    f32x16 oacc0 = (f32x16)0.0f, oacc1 = (f32x16)0.0f;

    for (int kt = 0; kt < 32; kt++) {
        // ---- S^T = K Q^T : sacc[nb][reg] = S[key=kt*64+nb*32+crow(reg,hi)][q0+c]
        f32x16 sacc0 = (f32x16)0.0f, sacc1 = (f32x16)0.0f;
#pragma unroll
        for (int ds = 0; ds < 4; ds++) {
            bf16x8 kf0 = *reinterpret_cast<const bf16x8*>(
                Kb + (size_t)(kt * 64 + c) * 64 + ds * 16 + hi * 8);
            bf16x8 kf1 = *reinterpret_cast<const bf16x8*>(
                Kb + (size_t)(kt * 64 + 32 + c) * 64 + ds * 16 + hi * 8);
            sacc0 = MFMA32(kf0, qf[ds], sacc0);
            sacc1 = MFMA32(kf1, qf[ds], sacc1);
        }

        // ---- issue V B-fragments now; used only after softmax (latency hidden)
        bf16x8 vf[2][4];
#pragma unroll
        for (int dn = 0; dn < 2; dn++)
#pragma unroll
            for (int ks = 0; ks < 4; ks++)
                vf[dn][ks] = *reinterpret_cast<const bf16x8*>(
                    Vb + (size_t)(dn * 32 + c) * 2048 + kt * 64 + ks * 16 + hi * 8);

        // ---- scale + mask
        float p[32];
#pragma unroll
        for (int r = 0; r < 16; r++) {
            p[r]      = mk ? sacc0[r] * 0.125f : 1e-9f;
            p[16 + r] = mk ? sacc1[r] * 0.125f : 1e-9f;
        }

        // ---- row max (in-lane tree + one cross-hi shfl)
        float t[16];
#pragma unroll
        for (int j = 0; j < 16; j++) t[j] = fmaxf(p[j], p[j + 16]);
#pragma unroll
        for (int s = 8; s >= 1; s >>= 1)
#pragma unroll
            for (int j = 0; j < s; j++) t[j] = fmaxf(t[j], t[j + s]);
        float pmax = fmaxf(t[0], __shfl_xor(t[0], 32, 64));

        // ---- defer-max rescale (rare)
        if (__any(pmax - m > 8.0f)) {
            const float mn = fmaxf(m, pmax);
            const float alpha = __expf(m - mn);
            m = mn;
            l *= alpha;
#pragma unroll
            for (int reg = 0; reg < 16; reg++) {
                const float ar = __shfl(alpha, (reg & 3) + 8 * (reg >> 2) + 4 * hi, 64);
                oacc0[reg] *= ar;
                oacc1[reg] *= ar;
            }
        }

        // ---- exp + row sum
        float rs[16];
#pragma unroll
        for (int j = 0; j < 32; j++) p[j] = __expf(p[j] - m);
#pragma unroll
        for (int j = 0; j < 16; j++) rs[j] = p[j] + p[j + 16];
#pragma unroll
        for (int s = 8; s >= 1; s >>= 1)
#pragma unroll
            for (int j = 0; j < s; j++) rs[j] += rs[j + s];
        l += rs[0] + __shfl_xor(rs[0], 32, 64);

        // ---- pack P to bf16 A-fragments (in-register, zero LDS)
        uint32_t w0[8], w1[8];
#pragma unroll
        for (int i = 0; i < 8; i++) {
            w0[i] = pkbf(p[2 * i], p[2 * i + 1]);
            w1[i] = pkbf(p[16 + 2 * i], p[16 + 2 * i + 1]);
        }
        uint32_t s00 = __shfl_xor(hi ? w0[0] : w0[2], 32, 64);
        uint32_t s01 = __shfl_xor(hi ? w0[1] : w0[3], 32, 64);
        uint32_t s02 = __shfl_xor(hi ? w0[4] : w0[6], 32, 64);
        uint32_t s03 = __shfl_xor(hi ? w0[5] : w0[7], 32, 64);
        uint32_t s10 = __shfl_xor(hi ? w1[0] : w1[2], 32, 64);
        uint32_t s11 = __shfl_xor(hi ? w1[1] : w1[3], 32, 64);
        uint32_t s12 = __shfl_xor(hi ? w1[4] : w1[6], 32, 64);
        uint32_t s13 = __shfl_xor(hi ? w1[5] : w1[7], 32, 64);

        union { uint32_t u[4]; bf16x8 v; } pa[4];
        if (hi == 0) {
            pa[0].u[0] = w0[0]; pa[0].u[1] = w0[1]; pa[0].u[2] = s00; pa[0].u[3] = s01;
            pa[1].u[0] = w0[4]; pa[1].u[1] = w0[5]; pa[1].u[2] = s02; pa[1].u[3] = s03;
            pa[2].u[0] = w1[0]; pa[2].u[1] = w1[1]; pa[2].u[2] = s10; pa[2].u[3] = s11;
            pa[3].u[0] = w1[4]; pa[3].u[1] = w1[5]; pa[3].u[2] = s12; pa[3].u[3] = s13;
        } else {
            pa[0].u[0] = s00; pa[0].u[1] = s01; pa[0].u[2] = w0[2]; pa[0].u[3] = w0[3];
            pa[1].u[0] = s02; pa[1].u[1] = s03; pa[1].u[2] = w0[6]; pa[1].u[3] = w0[7];
            pa[2].u[0] = s10; pa[2].u[1] = s11; pa[2].u[2] = w1[2]; pa[2].u[3] = w1[3];
            pa[3].u[0] = s12; pa[3].u[1] = s13; pa[3].u[2] = w1[6]; pa[3].u[3] = w1[7];
        }

        // ---- O += P V
#pragma unroll
        for (int ks = 0; ks < 4; ks++) {
            oacc0 = MFMA32(pa[ks].v, vf[0][ks], oacc0);
            oacc1 = MFMA32(pa[ks].v, vf[1][ks], oacc1);
        }
    }

    // ---- normalize + write O (fp32, [B,S,1024])
    const float invl = 1.0f / l;
#pragma unroll
    for (int reg = 0; reg < 16; reg++) {
        const int rr = (reg & 3) + 8 * (reg >> 2) + 4 * hi;
        const float ir = __shfl(invl, rr, 64);
        const size_t rowoff = (size_t)(b * 2048 + q0 + rr) * 1024 + h * 64 + c;
        O[rowoff]      = oacc0[reg] * ir;
        O[rowoff + 32] = oacc1[reg] * ir;
    }
}

// ---------------------------------------------------------------------------
// Residual + LayerNorm: out = LN(O + queries) * gamma + beta, per row of 1024.
// ---------------------------------------------------------------------------
__global__ __launch_bounds__(256) void resid_ln(const float* __restrict__ O,
                                                const float* __restrict__ Qin,
                                                const float* __restrict__ gamma,
                                                const float* __restrict__ beta,
                                                float* __restrict__ out) {
    __shared__ float red[4];
    const int row = blockIdx.x, tid = threadIdx.x;
    const size_t base = (size_t)row * 1024 + tid * 4;
    float4 o4 = *reinterpret_cast<const float4*>(O + base);
    float4 q4 = *reinterpret_cast<const float4*>(Qin + base);
    float x0 = o4.x + q4.x, x1 = o4.y + q4.y, x2 = o4.z + q4.z, x3 = o4.w + q4.w;

    float s = x0 + x1 + x2 + x3;
#pragma unroll
    for (int off = 32; off >= 1; off >>= 1) s += __shfl_xor(s, off, 64);
    const int w = tid >> 6;
    if ((tid & 63) == 0) red[w] = s;
    __syncthreads();
    const float mean = (red[0] + red[1] + red[2] + red[3]) * (1.0f / 1024.0f);
    __syncthreads();

    const float d0 = x0 - mean, d1 = x1 - mean, d2 = x2 - mean, d3 = x3 - mean;
    float vs = d0 * d0 + d1 * d1 + d2 * d2 + d3 * d3;
#pragma unroll
    for (int off = 32; off >= 1; off >>= 1) vs += __shfl_xor(vs, off, 64);
    if ((tid & 63) == 0) red[w] = vs;
    __syncthreads();
    const float var = (red[0] + red[1] + red[2] + red[3]) * (1.0f / 1024.0f);
    const float rstd = rsqrtf(var + 1e-5f);

    float4 g = *reinterpret_cast<const float4*>(gamma + tid * 4);
    float4 be = *reinterpret_cast<const float4*>(beta + tid * 4);
    float4 r;
    r.x = d0 * rstd * g.x + be.x;
    r.y = d1 * rstd * g.y + be.y;
    r.z = d2 * rstd * g.z + be.z;
    r.w = d3 * rstd * g.w + be.w;
    *reinterpret_cast<float4*>(out + base) = r;
}

// ---------------------------------------------------------------------------
extern "C" void kernel_launch(void* const* d_in, const int* in_sizes, int n_in,
                              void* d_out, int out_size, void* d_ws, size_t ws_size,
                              hipStream_t stream) {
    const float* q_in = (const float*)d_in[0];
    const float* k_in = (const float*)d_in[1];
    const float* v_in = (const float*)d_in[2];
    const int* mask = (const int*)d_in[3];
    const float* Wq = (const float*)d_in[4];
    const float* bq = (const float*)d_in[5];
    const float* Wk = (const float*)d_in[6];
    const float* bk = (const float*)d_in[7];
    const float* Wv = (const float*)d_in[8];
    const float* bv = (const float*)d_in[9];
    const float* gamma = (const float*)d_in[10];
    const float* beta = (const float*)d_in[11];
    float* out = (float*)d_out;

    unsigned short* wtq = (unsigned short*)d_ws;         // 1M bf16
    unsigned short* wtk = wtq + 1024 * 1024;
    unsigned short* wtv = wtk + 1024 * 1024;
    unsigned short* Qb = wtv + 1024 * 1024;              // 8M bf16 each
    unsigned short* Kb = Qb + 8192 * 1024;
    unsigned short* Vtb = Kb + 8192 * 1024;
    float* Obuf = (float*)(Vtb + 8192 * 1024);           // 8M fp32

    dim3 tb(256);
    wt_cast<<<dim3(32, 32), tb, 0, stream>>>(Wq, wtq);
    wt_cast<<<dim3(32, 32), tb, 0, stream>>>(Wk, wtk);
    wt_cast<<<dim3(32, 32), tb, 0, stream>>>(Wv, wtv);
    qkv_gemm<0><<<dim3(8, 64), tb, 0, stream>>>(q_in, wtq, bq, Qb);
    qkv_gemm<0><<<dim3(8, 64), tb, 0, stream>>>(k_in, wtk, bk, Kb);
    qkv_gemm<1><<<dim3(8, 64), tb, 0, stream>>>(v_in, wtv, bv, Vtb);
    flash_attn<<<dim3(16, 64), tb, 0, stream>>>(Qb, Kb, Vtb, mask, Obuf);
    resid_ln<<<dim3(8192), tb, 0, stream>>>(Obuf, q_in, gamma, beta, out);
}